// Round 6
// baseline (191.890 us; speedup 1.0000x reference)
//
#include <hip/hip_runtime.h>
#include <hip/hip_cooperative_groups.h>

namespace cg = cooperative_groups;

#define EMBED 256
#define NUM_DEPTH 128
#define CT_STRIDE 136   // 128 + 8 pad: keeps 16B alignment (272B rows), breaks pow-2 bank stride

typedef __attribute__((ext_vector_type(8))) short bf16x8;
typedef __attribute__((ext_vector_type(4))) float f32x4;

__device__ __forceinline__ unsigned short f2b(float f) {
    union { float f; unsigned u; } c; c.f = f;
    unsigned u = c.u;
    u += 0x7fffu + ((u >> 16) & 1u);   // RNE to bf16
    return (unsigned short)(u >> 16);
}
__device__ __forceinline__ float b2f(unsigned short h) {
    union { unsigned u; float f; } c; c.u = ((unsigned)h) << 16;
    return c.f;
}

// ================= Fused cooperative kernel: cvt -> gemm -> gather =================
// One launch instead of three: removes 2 kernel-boundary drains + 2 dispatch gaps
// (the unexplained ~15-20us of the per-iteration budget; all K-loop restructures
// r3-r5 were neutral, so the inner loop is NOT the controlling term). All phases
// are grid-stride, so any co-resident grid size is correct; grid is sized on host
// from the occupancy API. Phase B is the r5 GEMM core verbatim.
__global__ __launch_bounds__(256) void fused_kernel(
    const float* __restrict__ key, const float* __restrict__ value,
    const float* __restrict__ identity, const float* __restrict__ ref3d,
    const int* __restrict__ spatial, float* __restrict__ out,
    unsigned short* __restrict__ kb, unsigned short* __restrict__ vb,
    unsigned short* __restrict__ D, int nq, int nv)
{
    __shared__ __align__(16) unsigned short Ct[128 * CT_STRIDE];  // 34816 B
    unsigned short* As = Ct;          // [128][64] = 16 KB (aliased; dead outside K-loop)
    unsigned short* Bs = Ct + 8192;   // next 16 KB

    const int tid  = threadIdx.x;
    const int bid  = blockIdx.x;
    const int nblk = gridDim.x;
    cg::grid_group grid = cg::this_grid();

    // ---------------- Phase A: fp32 -> bf16 cvt of key & value ----------------
    {
        const int n4 = nq * (EMBED / 4);
        const float4* kf = (const float4*)key;
        const float4* vf = (const float4*)value;
        ushort4* ko = (ushort4*)kb;
        ushort4* vo = (ushort4*)vb;
        for (int i = bid * 256 + tid; i < n4; i += nblk * 256) {
            float4 a = kf[i], b = vf[i];
            ko[i] = make_ushort4(f2b(a.x), f2b(a.y), f2b(a.z), f2b(a.w));
            vo[i] = make_ushort4(f2b(b.x), f2b(b.y), f2b(b.z), f2b(b.w));
        }
    }
    grid.sync();

    // ---------------- Phase B: D = kb . vb^T (128x128 tiles, BK=64, swizzled) ----
    {
        const int lane = tid & 63;
        const int wave = tid >> 6;
        const int NBx = nv >> 7;
        const int ntile = (nq >> 7) * NBx;
        const int wm = (wave & 1) * 64;
        const int wn = (wave >> 1) * 64;
        const int fm = lane & 15;
        const int kg = lane >> 4;          // 0..3 (K quadrant of the MFMA fragment)

        // staging coords: 4 issues cover a 128x64 tile (16 KB) per matrix;
        // source granule pre-swizzled (g ^= row&7) so swizzled ds_reads are
        // conflict-free while LDS stays linear (rule #21 / m173).
        int srow[4], scol[4];
        #pragma unroll
        for (int j = 0; j < 4; ++j) {
            const int linear = j * 2048 + wave * 512 + lane * 8;
            srow[j] = linear >> 6;
            const int gl = (linear >> 3) & 7;
            scol[j] = ((gl ^ (srow[j] & 7)) << 3);
        }

        for (int t = bid; t < ntile; t += nblk) {
            const int m0 = (t / NBx) * 128;
            const int n0 = (t % NBx) * 128;
            f32x4 acc[4][4] = {};
            __syncthreads();   // Ct from any previous tile's epilogue is dead

            for (int kt = 0; kt < EMBED; kt += 64) {
                #pragma unroll
                for (int j = 0; j < 4; ++j) {
                    __builtin_amdgcn_global_load_lds(
                        (const __attribute__((address_space(1))) void*)
                            (kb + (size_t)(m0 + srow[j]) * EMBED + kt + scol[j]),
                        (__attribute__((address_space(3))) void*)(As + j * 2048 + wave * 512),
                        16, 0, 0);
                    __builtin_amdgcn_global_load_lds(
                        (const __attribute__((address_space(1))) void*)
                            (vb + (size_t)(n0 + srow[j]) * EMBED + kt + scol[j]),
                        (__attribute__((address_space(3))) void*)(Bs + j * 2048 + wave * 512),
                        16, 0, 0);
                }
                __syncthreads();

                #pragma unroll
                for (int s = 0; s < 2; ++s) {   // two K=32 sub-steps of the BK=64 tile
                    bf16x8 af[4], bfr[4];
                    #pragma unroll
                    for (int i = 0; i < 4; ++i) {
                        const int ra = wm + i * 16 + fm;
                        af[i]  = *(const bf16x8*)(As + ra * 64 + (((s * 4 + kg) ^ (ra & 7)) << 3));
                        const int rb = wn + i * 16 + fm;
                        bfr[i] = *(const bf16x8*)(Bs + rb * 64 + (((s * 4 + kg) ^ (rb & 7)) << 3));
                    }
                    #pragma unroll
                    for (int i = 0; i < 4; ++i)
                        #pragma unroll
                        for (int j = 0; j < 4; ++j)
                            acc[i][j] = __builtin_amdgcn_mfma_f32_16x16x32_bf16(af[i], bfr[j], acc[i][j], 0, 0, 0);
                }
                __syncthreads();
            }

            // epilogue: fragments -> Ct (bf16), then coalesced dwordx4 stores.
            // C/D layout: col=lane&15, row=(lane>>4)*4+r
            const int col = lane & 15;
            const int rbase = kg * 4;
            #pragma unroll
            for (int i = 0; i < 4; ++i)
                #pragma unroll
                for (int j = 0; j < 4; ++j) {
                    const int rr = wm + i * 16 + rbase;
                    const int cc = wn + j * 16 + col;
                    #pragma unroll
                    for (int r = 0; r < 4; ++r)
                        Ct[(rr + r) * CT_STRIDE + cc] = f2b(acc[i][j][r]);
                }
            __syncthreads();

            #pragma unroll
            for (int it = 0; it < 8; ++it) {
                const int r  = it * 16 + (tid >> 4);
                const int c8 = (tid & 15) * 8;
                const int4 v = *(const int4*)(Ct + r * CT_STRIDE + c8);
                *(int4*)(D + (size_t)(m0 + r) * nv + n0 + c8) = v;
            }
        }
    }
    grid.sync();

    // ---------------- Phase C: bilinear gather + identity (4 queries/group) ------
    {
        const int Hs = spatial[0], Ws = spatial[1];
        const int ngrp = nq >> 2;
        for (int g = bid; g < ngrp; g += nblk) {
            __syncthreads();   // Ct from phase B / previous group is dead
            const int q0 = g * 4;
            // coalesced stage: 4 D-rows = 4*nv ushorts (32 KB at nv=4096)
            const int4* src = (const int4*)(D + (size_t)q0 * nv);
            int4* dst = (int4*)Ct;
            const int nchunk = (4 * nv) >> 3;
            for (int i = tid; i < nchunk; i += 256) dst[i] = src[i];
            __syncthreads();

            #pragma unroll
            for (int h = 0; h < 2; ++h) {
                const int o = h * 256 + tid;               // 0..511 = 4 q * 128 d
                const int l = q0 * NUM_DEPTH + o;
                const int qi = o >> 7;
                const float2 r2 = reinterpret_cast<const float2*>(ref3d)[l];
                const float px = r2.x * (float)Ws - 0.5f;
                const float py = r2.y * (float)Hs - 0.5f;
                const float x0f = floorf(px), y0f = floorf(py);
                const int ix0 = (int)x0f, iy0 = (int)y0f;
                const int ix1 = ix0 + 1,  iy1 = iy0 + 1;
                const float wx1 = px - x0f, wx0 = 1.0f - wx1;
                const float wy1 = py - y0f, wy0 = 1.0f - wy1;
                const bool vx0 = (ix0 >= 0) & (ix0 < Ws);
                const bool vx1 = (ix1 >= 0) & (ix1 < Ws);
                const unsigned short* row = Ct + qi * nv;
                float acc = 0.f;
                if (iy0 >= 0 && iy0 < Hs) {
                    if (vx0) acc = fmaf(wy0 * wx0, b2f(row[iy0 * Ws + ix0]), acc);
                    if (vx1) acc = fmaf(wy0 * wx1, b2f(row[iy0 * Ws + ix1]), acc);
                }
                if (iy1 >= 0 && iy1 < Hs) {
                    if (vx0) acc = fmaf(wy1 * wx0, b2f(row[iy1 * Ws + ix0]), acc);
                    if (vx1) acc = fmaf(wy1 * wx1, b2f(row[iy1 * Ws + ix1]), acc);
                }
                out[l] = fmaf(acc, 0.0625f, identity[l]);  // 1/sqrt(256) = 1/16
            }
        }
    }
}

// ================= Fallback 3-kernel pipeline (r5, unchanged) =================
__global__ __launch_bounds__(256) void cvt_kernel(
    const float4* __restrict__ key, const float4* __restrict__ val,
    ushort4* __restrict__ kb, ushort4* __restrict__ vb, int n4)
{
    int i = blockIdx.x * blockDim.x + threadIdx.x;
    if (i >= n4) return;
    float4 a = key[i];
    float4 b = val[i];
    kb[i] = make_ushort4(f2b(a.x), f2b(a.y), f2b(a.z), f2b(a.w));
    vb[i] = make_ushort4(f2b(b.x), f2b(b.y), f2b(b.z), f2b(b.w));
}

__global__ __launch_bounds__(256) void gemm_nt_bf16(
    const unsigned short* __restrict__ A,
    const unsigned short* __restrict__ B,
    unsigned short* __restrict__ D, int N)
{
    __shared__ __align__(16) unsigned short Ct[128 * CT_STRIDE];
    unsigned short* As = Ct;
    unsigned short* Bs = Ct + 8192;

    const int m0 = blockIdx.y * 128;
    const int n0 = blockIdx.x * 128;
    const int tid  = threadIdx.x;
    const int lane = tid & 63;
    const int wave = tid >> 6;
    const int wm = (wave & 1) * 64;
    const int wn = (wave >> 1) * 64;
    const int fm = lane & 15;
    const int kg = lane >> 4;

    f32x4 acc[4][4] = {};

    int srow[4], scol[4];
    #pragma unroll
    for (int j = 0; j < 4; ++j) {
        const int linear = j * 2048 + wave * 512 + lane * 8;
        srow[j] = linear >> 6;
        const int gl = (linear >> 3) & 7;
        scol[j] = ((gl ^ (srow[j] & 7)) << 3);
    }

    for (int kt = 0; kt < EMBED; kt += 64) {
        #pragma unroll
        for (int j = 0; j < 4; ++j) {
            __builtin_amdgcn_global_load_lds(
                (const __attribute__((address_space(1))) void*)
                    (A + (size_t)(m0 + srow[j]) * EMBED + kt + scol[j]),
                (__attribute__((address_space(3))) void*)(As + j * 2048 + wave * 512),
                16, 0, 0);
            __builtin_amdgcn_global_load_lds(
                (const __attribute__((address_space(1))) void*)
                    (B + (size_t)(n0 + srow[j]) * EMBED + kt + scol[j]),
                (__attribute__((address_space(3))) void*)(Bs + j * 2048 + wave * 512),
                16, 0, 0);
        }
        __syncthreads();

        #pragma unroll
        for (int s = 0; s < 2; ++s) {
            bf16x8 af[4], bfr[4];
            #pragma unroll
            for (int i = 0; i < 4; ++i) {
                const int ra = wm + i * 16 + fm;
                af[i]  = *(const bf16x8*)(As + ra * 64 + (((s * 4 + kg) ^ (ra & 7)) << 3));
                const int rb = wn + i * 16 + fm;
                bfr[i] = *(const bf16x8*)(Bs + rb * 64 + (((s * 4 + kg) ^ (rb & 7)) << 3));
            }
            #pragma unroll
            for (int i = 0; i < 4; ++i)
                #pragma unroll
                for (int j = 0; j < 4; ++j)
                    acc[i][j] = __builtin_amdgcn_mfma_f32_16x16x32_bf16(af[i], bfr[j], acc[i][j], 0, 0, 0);
        }
        __syncthreads();
    }

    const int col = lane & 15;
    const int rbase = kg * 4;
    #pragma unroll
    for (int i = 0; i < 4; ++i)
        #pragma unroll
        for (int j = 0; j < 4; ++j) {
            const int rr = wm + i * 16 + rbase;
            const int cc = wn + j * 16 + col;
            #pragma unroll
            for (int r = 0; r < 4; ++r)
                Ct[(rr + r) * CT_STRIDE + cc] = f2b(acc[i][j][r]);
        }
    __syncthreads();

    #pragma unroll
    for (int it = 0; it < 8; ++it) {
        const int r  = it * 16 + (tid >> 4);
        const int c8 = (tid & 15) * 8;
        const int4 v = *(const int4*)(Ct + r * CT_STRIDE + c8);
        *(int4*)(D + (size_t)(m0 + r) * N + n0 + c8) = v;
    }
}

__global__ __launch_bounds__(256) void gather_kernel(
    const unsigned short* __restrict__ D,
    const float* __restrict__ identity,
    const float* __restrict__ ref3d,
    const int*   __restrict__ spatial,
    float* __restrict__ out, int nv)
{
    __shared__ unsigned short Ds[2 * 4096];

    const int q0 = blockIdx.x * 2;
    const int tid = threadIdx.x;

    const int4* src = (const int4*)(D + (size_t)q0 * nv);
    int4* dst = (int4*)Ds;
    const int nchunk = (2 * nv) / 8;
    for (int i = tid; i < nchunk; i += 256) dst[i] = src[i];
    __syncthreads();

    const int Hs = spatial[0], Ws = spatial[1];
    const int l = q0 * NUM_DEPTH + tid;
    const int qi = tid >> 7;

    const float2 r2 = reinterpret_cast<const float2*>(ref3d)[l];
    const float px = r2.x * (float)Ws - 0.5f;
    const float py = r2.y * (float)Hs - 0.5f;
    const float x0f = floorf(px), y0f = floorf(py);
    const int ix0 = (int)x0f, iy0 = (int)y0f;
    const int ix1 = ix0 + 1,  iy1 = iy0 + 1;
    const float wx1 = px - x0f, wx0 = 1.0f - wx1;
    const float wy1 = py - y0f, wy0 = 1.0f - wy1;
    const bool vx0 = (ix0 >= 0) & (ix0 < Ws);
    const bool vx1 = (ix1 >= 0) & (ix1 < Ws);

    const unsigned short* row = Ds + qi * nv;
    float acc = 0.f;
    if (iy0 >= 0 && iy0 < Hs) {
        if (vx0) acc = fmaf(wy0 * wx0, b2f(row[iy0 * Ws + ix0]), acc);
        if (vx1) acc = fmaf(wy0 * wx1, b2f(row[iy0 * Ws + ix1]), acc);
    }
    if (iy1 >= 0 && iy1 < Hs) {
        if (vx0) acc = fmaf(wy1 * wx0, b2f(row[iy1 * Ws + ix0]), acc);
        if (vx1) acc = fmaf(wy1 * wx1, b2f(row[iy1 * Ws + ix1]), acc);
    }
    out[l] = fmaf(acc, 0.0625f, identity[l]);
}

__global__ __launch_bounds__(256) void uv_direct_kernel(
    const float* __restrict__ key, const float* __restrict__ value,
    const float* __restrict__ identity, const float* __restrict__ ref3d,
    const int* __restrict__ spatial, float* __restrict__ out)
{
    const int q = blockIdx.x;
    const int tid = threadIdx.x;
    const int lane = tid & 63;
    const int wave = tid >> 6;
    const int H = spatial[0], W = spatial[1];
    const int row4 = EMBED / 4;
    const float4 k4 = reinterpret_cast<const float4*>(key + (size_t)q * EMBED)[lane];
    const float4* __restrict__ v4 = reinterpret_cast<const float4*>(value);
    for (int d = wave; d < NUM_DEPTH; d += 4) {
        const int l = q * NUM_DEPTH + d;
        const float rx = ref3d[2 * l], ry = ref3d[2 * l + 1];
        const float px = rx * (float)W - 0.5f, py = ry * (float)H - 0.5f;
        const float x0f = floorf(px), y0f = floorf(py);
        const int ix0 = (int)x0f, iy0 = (int)y0f, ix1 = ix0 + 1, iy1 = iy0 + 1;
        const float wx1 = px - x0f, wx0 = 1.f - wx1, wy1 = py - y0f, wy0 = 1.f - wy1;
        float4 acc = make_float4(0.f, 0.f, 0.f, 0.f);
        #define TAP(IY, IX, WGT) \
            if ((IY) >= 0 && (IY) < H && (IX) >= 0 && (IX) < W) { \
                const float w_ = (WGT); \
                const float4 t = v4[(size_t)((IY) * W + (IX)) * row4 + lane]; \
                acc.x = fmaf(w_, t.x, acc.x); acc.y = fmaf(w_, t.y, acc.y); \
                acc.z = fmaf(w_, t.z, acc.z); acc.w = fmaf(w_, t.w, acc.w); }
        TAP(iy0, ix0, wy0 * wx0) TAP(iy0, ix1, wy0 * wx1)
        TAP(iy1, ix0, wy1 * wx0) TAP(iy1, ix1, wy1 * wx1)
        #undef TAP
        float partial = acc.x * k4.x + acc.y * k4.y + acc.z * k4.z + acc.w * k4.w;
        #pragma unroll
        for (int off = 32; off > 0; off >>= 1) partial += __shfl_xor(partial, off, 64);
        if (lane == 0) out[l] = fmaf(partial, 0.0625f, identity[l]);
    }
}

extern "C" void kernel_launch(void* const* d_in, const int* in_sizes, int n_in,
                              void* d_out, int out_size, void* d_ws, size_t ws_size,
                              hipStream_t stream) {
    // inputs: 0 query(unused) 1 key 2 value 3 identity 4 ref_3d 5 spatial 6 W_attn(unused) 7 b_attn(unused)
    const float* key      = (const float*)d_in[1];
    const float* value    = (const float*)d_in[2];
    const float* identity = (const float*)d_in[3];
    const float* ref3d    = (const float*)d_in[4];
    const int*   spatial  = (const int*)d_in[5];
    float* out = (float*)d_out;

    const int nq = in_sizes[3] / NUM_DEPTH;   // 4096 queries
    const int nv = in_sizes[1] / EMBED;       // 4096 pixels (= H*W)

    const size_t d_bytes  = (size_t)nq * nv * sizeof(unsigned short);
    const size_t kb_bytes = (size_t)nq * EMBED * sizeof(unsigned short);
    const size_t vb_bytes = (size_t)nv * EMBED * sizeof(unsigned short);
    const size_t need = d_bytes + kb_bytes + vb_bytes;

    if (ws_size < need || (nq % 128) || (nv % 128) || nv > 4096 || (nq % 4) || nq != nv) {
        uv_direct_kernel<<<nq, 256, 0, stream>>>(key, value, identity, ref3d, spatial, out);
        return;
    }

    unsigned short* D  = (unsigned short*)d_ws;
    unsigned short* kb = (unsigned short*)((char*)d_ws + d_bytes);
    unsigned short* vb = (unsigned short*)((char*)d_ws + d_bytes + kb_bytes);

    // ---- cooperative fused path: grid sized once from the occupancy API ----
    static int coopBlocks = -2;   // -2 = not queried, -1/0 = unusable
    if (coopBlocks == -2) {
        int per = 0, dev = 0;
        hipDeviceProp_t prop;
        if (hipOccupancyMaxActiveBlocksPerMultiprocessor(&per, fused_kernel, 256, 0) == hipSuccess
            && per > 0
            && hipGetDevice(&dev) == hipSuccess
            && hipGetDeviceProperties(&prop, dev) == hipSuccess)
            coopBlocks = per * prop.multiProcessorCount;
        else
            coopBlocks = 0;
    }

    const int ntile = (nq / 128) * (nv / 128);
    if (coopBlocks > 0) {
        int nblk = coopBlocks < ntile ? coopBlocks : ntile;
        void* args[] = { (void*)&key, (void*)&value, (void*)&identity, (void*)&ref3d,
                         (void*)&spatial, (void*)&out, (void*)&kb, (void*)&vb,
                         (void*)&D, (void*)&nq, (void*)&nv };
        if (hipLaunchCooperativeKernel((void*)fused_kernel, dim3(nblk), dim3(256),
                                       args, 0, stream) == hipSuccess)
            return;
        coopBlocks = 0;   // launch rejected (e.g. capture restriction): use fallback
    }

    // ---- fallback: 3-kernel pipeline (r5 structure) ----
    const int n4 = nq * EMBED / 4;
    cvt_kernel<<<(n4 + 255) / 256, 256, 0, stream>>>(
        (const float4*)key, (const float4*)value, (ushort4*)kb, (ushort4*)vb, n4);
    dim3 grid(nv / 128, nq / 128);
    gemm_nt_bf16<<<grid, 256, 0, stream>>>(kb, vb, D, nv);
    gather_kernel<<<nq / 2, 256, 0, stream>>>(D, identity, ref3d, spatial, out, nv);
}

// Round 7
// 173.611 us; speedup vs baseline: 1.1053x; 1.1053x over previous
//
#include <hip/hip_runtime.h>

#define EMBED 256
#define NUM_DEPTH 128
#define CT_STRIDE 136   // 128 + 8 pad: keeps 16B alignment (272B rows), breaks pow-2 bank stride

typedef __attribute__((ext_vector_type(8))) short bf16x8;
typedef __attribute__((ext_vector_type(4))) float f32x4;

// self-cleaning cross-block counters (NOT in workspace -> never poisoned;
// zero-initialized at module load; reset to 0 by the 8th finisher each run,
// so graph replay always starts from a clean state).
__device__ int g_row_cnt[32];
__device__ int g_row_done[32];

__device__ __forceinline__ unsigned short f2b(float f) {
    union { float f; unsigned u; } c; c.f = f;
    unsigned u = c.u;
    u += 0x7fffu + ((u >> 16) & 1u);   // RNE to bf16
    return (unsigned short)(u >> 16);
}
__device__ __forceinline__ float b2f(unsigned short h) {
    union { unsigned u; float f; } c; c.u = ((unsigned)h) << 16;
    return c.f;
}

// ---------------- Phase 1: fp32 -> bf16 conversion of key & value ----------------
__global__ __launch_bounds__(256) void cvt_kernel(
    const float4* __restrict__ key, const float4* __restrict__ val,
    ushort4* __restrict__ kb, ushort4* __restrict__ vb, int n4)
{
    int i = blockIdx.x * blockDim.x + threadIdx.x;
    if (i >= n4) return;
    float4 a = key[i];
    float4 b = val[i];
    kb[i] = make_ushort4(f2b(a.x), f2b(a.y), f2b(a.z), f2b(a.w));
    vb[i] = make_ushort4(f2b(b.x), f2b(b.y), f2b(b.z), f2b(b.w));
}

// ------- Phase 2+3 fused: NT GEMM tiles + stream-k finisher gather ---------------
// GEMM core = r5 verbatim (128x128 tile, BK=64, both-sides swizzle, Ct repack).
// After a block stores its D tile: threadfence (wbl2) + atomicAdd(row_cnt[my row]).
// The last 8 blocks of a row become finishers: spin until row complete (producers
// are guaranteed-resident: spinners require 24 same-row producers already done),
// threadfence (inv), then each gathers 16 of the row's 128 queries using the dead
// Ct buffer as stage. Removes the gather kernel launch + its pipeline drain, and
// overlaps gather of early rows with GEMM of late rows. No grid.sync anywhere.
__global__ __launch_bounds__(256) void gemm_gather(
    const unsigned short* __restrict__ A,   // key bf16 [M][256]
    const unsigned short* __restrict__ B,   // value bf16 [N][256]
    unsigned short* __restrict__ D,         // [M][N] bf16
    const float* __restrict__ identity,     // [nq*128]
    const float* __restrict__ ref3d,        // [nq*128][2]
    const int*   __restrict__ spatial,      // {H, W}
    float* __restrict__ out,
    int N)
{
    __shared__ __align__(16) unsigned short Ct[128 * CT_STRIDE];  // 34816 B
    unsigned short* As = Ct;          // [128][64] = 16 KB (aliased; dead after K-loop)
    unsigned short* Bs = Ct + 8192;   // next 16 KB
    __shared__ int s_sig;

    const int NBx = gridDim.x;        // 32 column blocks per row
    const int row = blockIdx.y;
    const int m0 = row * 128;
    const int n0 = blockIdx.x * 128;
    const int tid  = threadIdx.x;
    const int lane = tid & 63;
    const int wave = tid >> 6;
    const int wm = (wave & 1) * 64;
    const int wn = (wave >> 1) * 64;
    const int fm = lane & 15;
    const int kg = lane >> 4;          // 0..3 (K quadrant of the MFMA fragment)

    f32x4 acc[4][4] = {};

    // staging coords: 4 issues cover a 128x64 tile (16 KB) per matrix; source
    // granule pre-swizzled (g ^= row&7) so swizzled ds_reads are conflict-free
    // while LDS stays linear (rule #21 / m173).
    int srow[4], scol[4];
    #pragma unroll
    for (int j = 0; j < 4; ++j) {
        const int linear = j * 2048 + wave * 512 + lane * 8;
        srow[j] = linear >> 6;
        const int gl = (linear >> 3) & 7;
        scol[j] = ((gl ^ (srow[j] & 7)) << 3);
    }

    for (int kt = 0; kt < EMBED; kt += 64) {
        #pragma unroll
        for (int j = 0; j < 4; ++j) {
            __builtin_amdgcn_global_load_lds(
                (const __attribute__((address_space(1))) void*)
                    (A + (size_t)(m0 + srow[j]) * EMBED + kt + scol[j]),
                (__attribute__((address_space(3))) void*)(As + j * 2048 + wave * 512),
                16, 0, 0);
            __builtin_amdgcn_global_load_lds(
                (const __attribute__((address_space(1))) void*)
                    (B + (size_t)(n0 + srow[j]) * EMBED + kt + scol[j]),
                (__attribute__((address_space(3))) void*)(Bs + j * 2048 + wave * 512),
                16, 0, 0);
        }
        __syncthreads();

        #pragma unroll
        for (int s = 0; s < 2; ++s) {      // two K=32 sub-steps of the BK=64 tile
            bf16x8 af[4], bfr[4];
            #pragma unroll
            for (int i = 0; i < 4; ++i) {
                const int ra = wm + i * 16 + fm;
                af[i]  = *(const bf16x8*)(As + ra * 64 + (((s * 4 + kg) ^ (ra & 7)) << 3));
                const int rb = wn + i * 16 + fm;
                bfr[i] = *(const bf16x8*)(Bs + rb * 64 + (((s * 4 + kg) ^ (rb & 7)) << 3));
            }
            #pragma unroll
            for (int i = 0; i < 4; ++i)
                #pragma unroll
                for (int j = 0; j < 4; ++j)
                    acc[i][j] = __builtin_amdgcn_mfma_f32_16x16x32_bf16(af[i], bfr[j], acc[i][j], 0, 0, 0);
        }
        __syncthreads();   // last iteration: also makes As/Bs dead -> Ct reuse safe
    }

    // ---- Epilogue: fragments -> Ct (bf16), then coalesced dwordx4 stores ----
    // C/D layout: col=lane&15, row=(lane>>4)*4+r
    const int col = lane & 15;
    const int rbase = kg * 4;
    #pragma unroll
    for (int i = 0; i < 4; ++i)
        #pragma unroll
        for (int j = 0; j < 4; ++j) {
            const int rr = wm + i * 16 + rbase;
            const int cc = wn + j * 16 + col;
            #pragma unroll
            for (int r = 0; r < 4; ++r)
                Ct[(rr + r) * CT_STRIDE + cc] = f2b(acc[i][j][r]);
        }
    __syncthreads();

    #pragma unroll
    for (int it = 0; it < 8; ++it) {
        const int r  = it * 16 + (tid >> 4);   // 0..127
        const int c8 = (tid & 15) * 8;         // 8-ushort chunk
        const int4 v = *(const int4*)(Ct + r * CT_STRIDE + c8);
        *(int4*)(D + (size_t)(m0 + r) * N + n0 + c8) = v;
    }
    __syncthreads();   // all D-tile stores issued (each wave's vmcnt drained)

    // ---- signal tile completion (release: wbl2 then device-scope atomic) ----
    if (tid == 0) {
        __threadfence();                        // write back our tile to L3
        s_sig = atomicAdd(&g_row_cnt[row], 1);  // device-scope by default (m20)
    }
    __syncthreads();
    const int old = s_sig;
    if (old < NBx - 8) return;                  // not a finisher
    const int slice = old - (NBx - 8);          // 0..7: my 16-query slice

    // ---- wait for the full row, then acquire (inv stale L2 lines) ----
    if (tid == 0) {
        while (__hip_atomic_load(&g_row_cnt[row], __ATOMIC_RELAXED,
                                 __HIP_MEMORY_SCOPE_AGENT) < NBx)
            __builtin_amdgcn_s_sleep(2);
        __threadfence();
    }
    __syncthreads();

    // ---- gather 16 queries: 8 x {stage 2 D-rows (16 KB) into Ct, 256 taps} ----
    const int Hs = spatial[0], Ws = spatial[1];
    const int qi = tid >> 7;                    // 0 or 1
    for (int g = 0; g < 8; ++g) {
        const int q0 = m0 + slice * 16 + g * 2;
        const int4* src = (const int4*)(D + (size_t)q0 * N);
        int4* dst = (int4*)Ct;
        const int nchunk = (2 * N) >> 3;
        for (int i = tid; i < nchunk; i += 256) dst[i] = src[i];
        __syncthreads();

        const int l = q0 * NUM_DEPTH + tid;     // 256 threads == 2 q * 128 d
        const float2 r2 = reinterpret_cast<const float2*>(ref3d)[l];
        const float px = r2.x * (float)Ws - 0.5f;
        const float py = r2.y * (float)Hs - 0.5f;
        const float x0f = floorf(px), y0f = floorf(py);
        const int ix0 = (int)x0f, iy0 = (int)y0f;
        const int ix1 = ix0 + 1,  iy1 = iy0 + 1;
        const float wx1 = px - x0f, wx0 = 1.0f - wx1;
        const float wy1 = py - y0f, wy0 = 1.0f - wy1;
        const bool vx0 = (ix0 >= 0) & (ix0 < Ws);
        const bool vx1 = (ix1 >= 0) & (ix1 < Ws);

        const unsigned short* rowp = Ct + qi * N;
        float accv = 0.f;
        if (iy0 >= 0 && iy0 < Hs) {
            if (vx0) accv = fmaf(wy0 * wx0, b2f(rowp[iy0 * Ws + ix0]), accv);
            if (vx1) accv = fmaf(wy0 * wx1, b2f(rowp[iy0 * Ws + ix1]), accv);
        }
        if (iy1 >= 0 && iy1 < Hs) {
            if (vx0) accv = fmaf(wy1 * wx0, b2f(rowp[iy1 * Ws + ix0]), accv);
            if (vx1) accv = fmaf(wy1 * wx1, b2f(rowp[iy1 * Ws + ix1]), accv);
        }
        out[l] = fmaf(accv, 0.0625f, identity[l]);  // 1/sqrt(256) = 1/16
        __syncthreads();   // Ct reused next iteration
    }

    // ---- self-clean: the 8th finisher of this row resets both counters ----
    if (tid == 0) {
        if (atomicAdd(&g_row_done[row], 1) == 7) {
            __hip_atomic_store(&g_row_cnt[row], 0, __ATOMIC_RELAXED,
                               __HIP_MEMORY_SCOPE_AGENT);
            __hip_atomic_store(&g_row_done[row], 0, __ATOMIC_RELAXED,
                               __HIP_MEMORY_SCOPE_AGENT);
        }
    }
}

// ---------------- Fallback (round-1 direct kernel) ----------------
__global__ __launch_bounds__(256) void uv_direct_kernel(
    const float* __restrict__ key, const float* __restrict__ value,
    const float* __restrict__ identity, const float* __restrict__ ref3d,
    const int* __restrict__ spatial, float* __restrict__ out)
{
    const int q = blockIdx.x;
    const int tid = threadIdx.x;
    const int lane = tid & 63;
    const int wave = tid >> 6;
    const int H = spatial[0], W = spatial[1];
    const int row4 = EMBED / 4;
    const float4 k4 = reinterpret_cast<const float4*>(key + (size_t)q * EMBED)[lane];
    const float4* __restrict__ v4 = reinterpret_cast<const float4*>(value);
    for (int d = wave; d < NUM_DEPTH; d += 4) {
        const int l = q * NUM_DEPTH + d;
        const float rx = ref3d[2 * l], ry = ref3d[2 * l + 1];
        const float px = rx * (float)W - 0.5f, py = ry * (float)H - 0.5f;
        const float x0f = floorf(px), y0f = floorf(py);
        const int ix0 = (int)x0f, iy0 = (int)y0f, ix1 = ix0 + 1, iy1 = iy0 + 1;
        const float wx1 = px - x0f, wx0 = 1.f - wx1, wy1 = py - y0f, wy0 = 1.f - wy1;
        float4 acc = make_float4(0.f, 0.f, 0.f, 0.f);
        #define TAP(IY, IX, WGT) \
            if ((IY) >= 0 && (IY) < H && (IX) >= 0 && (IX) < W) { \
                const float w_ = (WGT); \
                const float4 t = v4[(size_t)((IY) * W + (IX)) * row4 + lane]; \
                acc.x = fmaf(w_, t.x, acc.x); acc.y = fmaf(w_, t.y, acc.y); \
                acc.z = fmaf(w_, t.z, acc.z); acc.w = fmaf(w_, t.w, acc.w); }
        TAP(iy0, ix0, wy0 * wx0) TAP(iy0, ix1, wy0 * wx1)
        TAP(iy1, ix0, wy1 * wx0) TAP(iy1, ix1, wy1 * wx1)
        #undef TAP
        float partial = acc.x * k4.x + acc.y * k4.y + acc.z * k4.z + acc.w * k4.w;
        #pragma unroll
        for (int off = 32; off > 0; off >>= 1) partial += __shfl_xor(partial, off, 64);
        if (lane == 0) out[l] = fmaf(partial, 0.0625f, identity[l]);
    }
}

extern "C" void kernel_launch(void* const* d_in, const int* in_sizes, int n_in,
                              void* d_out, int out_size, void* d_ws, size_t ws_size,
                              hipStream_t stream) {
    // inputs: 0 query(unused) 1 key 2 value 3 identity 4 ref_3d 5 spatial 6 W_attn(unused) 7 b_attn(unused)
    const float* key      = (const float*)d_in[1];
    const float* value    = (const float*)d_in[2];
    const float* identity = (const float*)d_in[3];
    const float* ref3d    = (const float*)d_in[4];
    const int*   spatial  = (const int*)d_in[5];
    float* out = (float*)d_out;

    const int nq = in_sizes[3] / NUM_DEPTH;   // 4096 queries
    const int nv = in_sizes[1] / EMBED;       // 4096 pixels (= H*W)

    const size_t d_bytes  = (size_t)nq * nv * sizeof(unsigned short);
    const size_t kb_bytes = (size_t)nq * EMBED * sizeof(unsigned short);
    const size_t vb_bytes = (size_t)nv * EMBED * sizeof(unsigned short);
    const size_t need = d_bytes + kb_bytes + vb_bytes;

    // finisher pattern needs: 128-divisible, nv/128 >= 9 (last-8 slicing),
    // nq/128 <= 32 (counter arrays), nq == nv (shapes assumed square here).
    if (ws_size < need || (nq % 128) || (nv % 128) || nv > 4096 || nq > 4096 ||
        nq != nv || (nv / 128) < 9) {
        uv_direct_kernel<<<nq, 256, 0, stream>>>(key, value, identity, ref3d, spatial, out);
        return;
    }

    unsigned short* D  = (unsigned short*)d_ws;
    unsigned short* kb = (unsigned short*)((char*)d_ws + d_bytes);
    unsigned short* vb = (unsigned short*)((char*)d_ws + d_bytes + kb_bytes);

    // Phase 1: convert key & value to bf16
    const int n4 = nq * EMBED / 4;
    cvt_kernel<<<(n4 + 255) / 256, 256, 0, stream>>>(
        (const float4*)key, (const float4*)value, (ushort4*)kb, (ushort4*)vb, n4);

    // Phase 2+3 fused: GEMM tiles + stream-k finisher gather (one launch)
    dim3 grid(nv / 128, nq / 128);
    gemm_gather<<<grid, 256, 0, stream>>>(kb, vb, D, identity, ref3d, spatial, out, nv);
}